// Round 1
// 362.328 us; speedup vs baseline: 1.2089x; 1.2089x over previous
//
#include <hip/hip_runtime.h>

#define HH 256
#define WW 256
#define BATCH 8
#define CH 64
#define NIMG (BATCH*CH)      // 512
#define HWSZ (HH*WW)         // 65536
#define SCL (1.0f/12.0f)
#define KH 0.04f
#define TFRAC 0.7f
#define RS 16                // rows per thread-tile in K1
#define NEGINF (-__builtin_inff())

// order-preserving float->uint encoding for atomicMax
__device__ __forceinline__ unsigned encf(float f) {
    unsigned u = __float_as_uint(f);
    return (u & 0x80000000u) ? ~u : (u | 0x80000000u);
}
__device__ __forceinline__ float decf(unsigned u) {
    return __uint_as_float((u & 0x80000000u) ? (u & 0x7fffffffu) : ~u);
}

// K1: register-rolling Harris. Thread = 4 cols x RS rows tile. No LDS (except
// 16B for the block max). Writes vertically-dilated R (Rv) into `rv` (=d_out)
// and per-image max R via atomicMax.  (unchanged this round)
__global__ __launch_bounds__(256) void k1(const float* __restrict__ x,
                                          float* __restrict__ rv,
                                          unsigned* __restrict__ ms)
{
    const int tid = threadIdx.x;
    const int img = blockIdx.x >> 2;                     // 4 blocks per image
    const int tx  = tid & 63;                            // col chunk (4 cols)
    const int sy  = ((blockIdx.x & 3) << 2) | (tid >> 6);// row slab 0..15 (wave-uniform)
    const int r0  = sy * RS;
    const int c0  = tx * 4;
    const float* ib = x + (size_t)img * HWSZ;
    float* rb = rv + (size_t)img * HWSZ;

    float im[3][8];                        // img rows, cols c0-2..c0+5
    float px[3][6], pq[3][6], py[3][6];    // products xx,xy,yy, cols c0-1..c0+4
    float R[3][4];                         // R rows window, cols c0..c0+3
    float rmax = NEGINF;

    auto loadrow = [&](int gr, float* d) {
        gr = gr < 0 ? -gr : (gr >= HH ? 2*HH - 2 - gr : gr);   // reflect101
        const float* rp = ib + gr * WW;
        float4 own = *(const float4*)(rp + c0);
        float4 lf  = (tx > 0)  ? *(const float4*)(rp + c0 - 4) : own;
        float4 rt  = (tx < 63) ? *(const float4*)(rp + c0 + 4) : own;
        d[0] = (tx > 0)  ? lf.z : own.z;   // col -2 -> reflect 2
        d[1] = (tx > 0)  ? lf.w : own.y;   // col -1 -> reflect 1
        d[2] = own.x; d[3] = own.y; d[4] = own.z; d[5] = own.w;
        d[6] = (tx < 63) ? rt.x : own.z;   // col 256 -> reflect 254
        d[7] = (tx < 63) ? rt.y : own.y;   // col 257 -> reflect 253
    };

    loadrow(r0 - 3, im[0]);
    loadrow(r0 - 2, im[1]);

#pragma unroll
    for (int i = 0; i < RS + 4; ++i) {
        const int m = r0 - 2 + i;          // product-row index this step
        loadrow(m + 1, im[(2 + i) % 3]);

        // products row m from img rows m-1,m,m+1 (slots i%3,(i+1)%3,(i+2)%3)
        {
            const int ia = i % 3, ib2 = (i + 1) % 3, ic = (i + 2) % 3;
            float t1[8], t2[8];
#pragma unroll
            for (int q = 0; q < 8; ++q) {
                t1[q] = im[ia][q] + 2.0f * im[ib2][q] + im[ic][q];
                t2[q] = im[ic][q] - im[ia][q];
            }
            const int po = i % 3;
#pragma unroll
            for (int q = 0; q < 6; ++q) {
                float dx = SCL * (t1[q + 2] - t1[q]);
                float dy = SCL * (t2[q] + 2.0f * t2[q + 1] + t2[q + 2]);
                px[po][q] = dx * dx;
                pq[po][q] = dx * dy;
                py[po][q] = dy * dy;
            }
            // Box stage reflects the product FIELD: pxy(-1) = +pxy(1), but
            // recomputing from the reflected image gives -pxy(1) (dx odd, dy
            // even under column reflection). pxx/pyy are even -> already OK.
            if (tx == 0)  pq[po][0] = -pq[po][0];   // col -1
            if (tx == 63) pq[po][5] = -pq[po][5];   // col 256
        }

        // R row s = m-1 (p rows s-1,s,s+1 at slots (i+1)%3,(i+2)%3,i%3)
        if (i >= 2) {
            const int s = m - 1;
            const int A = (i + 1) % 3, B2 = (i + 2) % 3, C2 = i % 3;
            float Sxx[6], Sxy[6], Syy[6];
            if (s == 0) {            // product-field reflect: S(0)=p0+2*p1
#pragma unroll
                for (int q = 0; q < 6; ++q) {
                    Sxx[q] = px[B2][q] + 2.0f * px[C2][q];
                    Sxy[q] = pq[B2][q] + 2.0f * pq[C2][q];
                    Syy[q] = py[B2][q] + 2.0f * py[C2][q];
                }
            } else if (s == HH - 1) { // S(255)=2*p254+p255
#pragma unroll
                for (int q = 0; q < 6; ++q) {
                    Sxx[q] = 2.0f * px[A][q] + px[B2][q];
                    Sxy[q] = 2.0f * pq[A][q] + pq[B2][q];
                    Syy[q] = 2.0f * py[A][q] + py[B2][q];
                }
            } else {
#pragma unroll
                for (int q = 0; q < 6; ++q) {
                    Sxx[q] = px[A][q] + px[B2][q] + px[C2][q];
                    Sxy[q] = pq[A][q] + pq[B2][q] + pq[C2][q];
                    Syy[q] = py[A][q] + py[B2][q] + py[C2][q];
                }
            }
            const bool vs = (s >= 0) && (s < HH);   // wave-uniform
#pragma unroll
            for (int j = 0; j < 4; ++j) {
                float ixx = Sxx[j] + Sxx[j + 1] + Sxx[j + 2];
                float ixy = Sxy[j] + Sxy[j + 1] + Sxy[j + 2];
                float iyy = Syy[j] + Syy[j + 1] + Syy[j + 2];
                float tr = ixx + iyy;
                float Rj = (ixx * iyy - ixy * ixy) - KH * tr * tr;
                Rj = vs ? Rj : NEGINF;
                R[i % 3][j] = Rj;
                rmax = fmaxf(rmax, Rj);
            }
        }

        // Rv row r = m-2 (R rows r-1,r,r+1 at slots (i+1)%3,(i+2)%3,i%3)
        if (i >= 4) {
            const int r = r0 - 4 + i;       // in [r0, r0+RS-1]
            const int A = (i + 1) % 3, B2 = (i + 2) % 3, C2 = i % 3;
            float4 o;
            o.x = fmaxf(fmaxf(R[A][0], R[B2][0]), R[C2][0]);
            o.y = fmaxf(fmaxf(R[A][1], R[B2][1]), R[C2][1]);
            o.z = fmaxf(fmaxf(R[A][2], R[B2][2]), R[C2][2]);
            o.w = fmaxf(fmaxf(R[A][3], R[B2][3]), R[C2][3]);
            *(float4*)(rb + r * WW + c0) = o;
        }
    }

    // per-image max (block spans exactly one image)
#pragma unroll
    for (int off = 32; off; off >>= 1) rmax = fmaxf(rmax, __shfl_xor(rmax, off));
    __shared__ float sm[4];
    if ((tid & 63) == 0) sm[tid >> 6] = rmax;
    __syncthreads();
    if (tid == 0) {
        float mm = fmaxf(fmaxf(sm[0], sm[1]), fmaxf(sm[2], sm[3]));
        atomicMax(ms + img, encf(mm));
    }
}

// K2 (new): block = one (b,h) row, 512 threads / 8 waves.
// Stage x[64ch][256px] (64KB) + W[64][64] (16KB) in LDS once; wave w computes
// out-channels 8w..8w+7, lane l pixels 4l..4l+3 (acc 8x4 in VGPRs). x values
// get 8x reuse from LDS; W reads are wave-uniform broadcasts. Epilogue does
// horizontal dilate via shuffles (race-free: each wave touches only its own
// channel rows), threshold, combine, float4 store. Accumulation order over ci
// identical to previous version -> bitwise-same conv result.
__global__ __launch_bounds__(512, 4) void k2(const float* __restrict__ x,
                                             const float* __restrict__ wgt,
                                             const float* __restrict__ bias,
                                             const unsigned* __restrict__ ms,
                                             float* __restrict__ io)
{
    __shared__ __align__(16) float Xl[CH][WW];   // 64 KiB
    __shared__ __align__(16) float Wl[CH][CH];   // 16 KiB
    const int tid = threadIdx.x;
    const int wv  = tid >> 6;        // wave 0..7
    const int l   = tid & 63;        // lane 0..63
    const int b   = blockIdx.x >> 8;
    const int h   = blockIdx.x & 255;
    const int oc0 = wv << 3;         // this wave's first out-channel

    // ---- stage x row-block + weights into LDS (coalesced, conflict-free) ----
    {
        const float* xrow = x + (size_t)b * CH * HWSZ + (size_t)h * WW + (l << 2);
        float4 tmp[8];
#pragma unroll
        for (int k = 0; k < 8; ++k)
            tmp[k] = *(const float4*)(xrow + (size_t)(oc0 + k) * HWSZ);
#pragma unroll
        for (int k = 0; k < 8; ++k)
            *(float4*)&Xl[oc0 + k][l << 2] = tmp[k];

        const float4* wg4 = (const float4*)wgt;        // 4096 floats = 1024 float4
        float4* wl4 = (float4*)&Wl[0][0];
        float4 w0 = wg4[tid], w1 = wg4[tid + 512];
        wl4[tid] = w0; wl4[tid + 512] = w1;
    }
    __syncthreads();

    // ---- conv1x1: acc[j][k] = bias + sum_ci W[oc0+j][ci] * x[ci][4l+k] ----
    float acc[8][4];
#pragma unroll
    for (int j = 0; j < 8; ++j) {
        const float bj = bias[oc0 + j];
        acc[j][0] = bj; acc[j][1] = bj; acc[j][2] = bj; acc[j][3] = bj;
    }
#pragma unroll 4
    for (int c2 = 0; c2 < CH; c2 += 2) {
        const float4 xa = *(const float4*)&Xl[c2][l << 2];
        const float4 xb = *(const float4*)&Xl[c2 + 1][l << 2];
#pragma unroll
        for (int j = 0; j < 8; ++j) {
            const float2 wj = *(const float2*)&Wl[oc0 + j][c2];
            acc[j][0] = fmaf(wj.x, xa.x, acc[j][0]);
            acc[j][1] = fmaf(wj.x, xa.y, acc[j][1]);
            acc[j][2] = fmaf(wj.x, xa.z, acc[j][2]);
            acc[j][3] = fmaf(wj.x, xa.w, acc[j][3]);
            acc[j][0] = fmaf(wj.y, xb.x, acc[j][0]);
            acc[j][1] = fmaf(wj.y, xb.y, acc[j][1]);
            acc[j][2] = fmaf(wj.y, xb.z, acc[j][2]);
            acc[j][3] = fmaf(wj.y, xb.w, acc[j][3]);
        }
    }

    // ---- epilogue: horizontal dilate of Rv + threshold + combine ----
    const size_t pb = (size_t)b * CH * HWSZ + (size_t)h * WW + (size_t)(l << 2);
    float4 rvv[8];
#pragma unroll
    for (int j = 0; j < 8; ++j)
        rvv[j] = *(const float4*)(io + pb + (size_t)(oc0 + j) * HWSZ);

#pragma unroll
    for (int j = 0; j < 8; ++j) {
        const int c = oc0 + j;
        float lf = __shfl_up(rvv[j].w, 1);
        float rt = __shfl_down(rvv[j].x, 1);
        if (l == 0)  lf = NEGINF;    // col -1: border does not contribute
        if (l == 63) rt = NEGINF;    // col 256
        const float d0 = fmaxf(fmaxf(lf,       rvv[j].x), rvv[j].y);
        const float d1 = fmaxf(fmaxf(rvv[j].x, rvv[j].y), rvv[j].z);
        const float d2 = fmaxf(fmaxf(rvv[j].y, rvv[j].z), rvv[j].w);
        const float d3 = fmaxf(fmaxf(rvv[j].z, rvv[j].w), rt);
        const float t = TFRAC * decf(ms[b * CH + c]);
        const float4 xi = *(const float4*)&Xl[c][l << 2];
        const float y0 = fmaxf(acc[j][0], 0.0f);
        const float y1 = fmaxf(acc[j][1], 0.0f);
        const float y2 = fmaxf(acc[j][2], 0.0f);
        const float y3 = fmaxf(acc[j][3], 0.0f);
        float4 o;
        o.x = fmaf(d0 > t ? 1.0f : (d0 < t ? 0.0f : xi.x), y0, xi.x);
        o.y = fmaf(d1 > t ? 1.0f : (d1 < t ? 0.0f : xi.y), y1, xi.y);
        o.z = fmaf(d2 > t ? 1.0f : (d2 < t ? 0.0f : xi.z), y2, xi.z);
        o.w = fmaf(d3 > t ? 1.0f : (d3 < t ? 0.0f : xi.w), y3, xi.w);
        *(float4*)(io + pb + (size_t)c * HWSZ) = o;
    }
}

extern "C" void kernel_launch(void* const* d_in, const int* in_sizes, int n_in,
                              void* d_out, int out_size, void* d_ws, size_t ws_size,
                              hipStream_t stream)
{
    const float* x    = (const float*)d_in[0];
    const float* wgt  = (const float*)d_in[1];
    const float* bias = (const float*)d_in[2];
    float* out = (float*)d_out;
    unsigned* ms = (unsigned*)d_ws;

    // enc(x)=0u is below the encoding of any real float -> memset works as init
    hipMemsetAsync(ms, 0, NIMG * sizeof(unsigned), stream);
    hipLaunchKernelGGL(k1, dim3(NIMG * 4), dim3(256), 0, stream, x, out, ms);
    hipLaunchKernelGGL(k2, dim3(BATCH * HH), dim3(512), 0, stream,
                       x, wgt, bias, ms, out);
}

// Round 2
// 328.955 us; speedup vs baseline: 1.3316x; 1.1015x over previous
//
#include <hip/hip_runtime.h>

#define HH 256
#define WW 256
#define BATCH 8
#define CH 64
#define NIMG (BATCH*CH)      // 512
#define HWSZ (HH*WW)         // 65536
#define SCL (1.0f/12.0f)
#define KH 0.04f
#define TFRAC 0.7f
#define RS 16                // rows per thread-tile in K1
#define NEGINF (-__builtin_inff())

// K1: register-rolling Harris. Thread = 4 cols x RS rows; one wave = full
// 256-col width of a row slab, so column halos come from neighbor lanes via
// shuffle (1 float4 load per row instead of 3). Products are folded to
// horizontal 3-sums immediately (h* arrays) - the box stage only needs those.
// Each block (4 slabs = 64 rows) plain-stores its max to ms[img*4+slab]:
// no atomics, no init kernel.
__global__ __launch_bounds__(256) void k1(const float* __restrict__ x,
                                          float* __restrict__ rv,
                                          float* __restrict__ ms)
{
    const int tid = threadIdx.x;
    const int img = blockIdx.x >> 2;                     // 4 blocks per image
    const int tx  = tid & 63;                            // col chunk (4 cols)
    const int sy  = ((blockIdx.x & 3) << 2) | (tid >> 6);// row slab 0..15 (wave-uniform)
    const int r0  = sy * RS;
    const int c0  = tx * 4;
    const float* ib = x + (size_t)img * HWSZ;
    float* rb = rv + (size_t)img * HWSZ;

    float im[3][8];                        // img rows, cols c0-2..c0+5
    float hx[3][4], hq[3][4], hy[3][4];    // horizontal 3-sums of products, cols c0..c0+3
    float R[3][4];                         // R rows window, cols c0..c0+3
    float rmax = NEGINF;

    auto loadrow = [&](int gr, float* d) {
        gr = gr < 0 ? -gr : (gr >= HH ? 2*HH - 2 - gr : gr);   // reflect101
        float4 own = *(const float4*)(ib + gr * WW + c0);
        float upz = __shfl_up(own.z, 1);     // lane-1 col 4l-2
        float upw = __shfl_up(own.w, 1);     // lane-1 col 4l-1
        float dnx = __shfl_down(own.x, 1);   // lane+1 col 4l+4
        float dny = __shfl_down(own.y, 1);   // lane+1 col 4l+5
        d[0] = (tx > 0)  ? upz : own.z;      // col -2 -> reflect 2
        d[1] = (tx > 0)  ? upw : own.y;      // col -1 -> reflect 1
        d[2] = own.x; d[3] = own.y; d[4] = own.z; d[5] = own.w;
        d[6] = (tx < 63) ? dnx : own.z;      // col 256 -> reflect 254
        d[7] = (tx < 63) ? dny : own.y;      // col 257 -> reflect 253
    };

    loadrow(r0 - 3, im[0]);
    loadrow(r0 - 2, im[1]);

#pragma unroll
    for (int i = 0; i < RS + 4; ++i) {
        const int m = r0 - 2 + i;          // product-row index this step
        loadrow(m + 1, im[(2 + i) % 3]);

        // products row m from img rows m-1,m,m+1; fold to horizontal 3-sums
        {
            const int ia = i % 3, ib2 = (i + 1) % 3, ic = (i + 2) % 3;
            float t1[8], t2[8];
#pragma unroll
            for (int q = 0; q < 8; ++q) {
                t1[q] = im[ia][q] + 2.0f * im[ib2][q] + im[ic][q];
                t2[q] = im[ic][q] - im[ia][q];
            }
            float pxv[6], pqv[6], pyv[6];
#pragma unroll
            for (int q = 0; q < 6; ++q) {
                float dx = SCL * (t1[q + 2] - t1[q]);
                float dy = SCL * (t2[q] + 2.0f * t2[q + 1] + t2[q + 2]);
                pxv[q] = dx * dx;
                pqv[q] = dx * dy;
                pyv[q] = dy * dy;
            }
            // Box stage reflects the product FIELD: pxy(-1) = +pxy(1), but
            // recomputing from the reflected image gives -pxy(1) (dx odd, dy
            // even under column reflection). pxx/pyy are even -> already OK.
            if (tx == 0)  pqv[0] = -pqv[0];   // col -1
            if (tx == 63) pqv[5] = -pqv[5];   // col 256
            const int po = i % 3;
#pragma unroll
            for (int j = 0; j < 4; ++j) {
                hx[po][j] = pxv[j] + pxv[j + 1] + pxv[j + 2];
                hq[po][j] = pqv[j] + pqv[j + 1] + pqv[j + 2];
                hy[po][j] = pyv[j] + pyv[j + 1] + pyv[j + 2];
            }
        }

        // R row s = m-1 (h rows s-1,s,s+1 at slots (i+1)%3,(i+2)%3,i%3)
        if (i >= 2) {
            const int s = m - 1;
            const int A = (i + 1) % 3, B2 = (i + 2) % 3, C2 = i % 3;
            const bool vs = (s >= 0) && (s < HH);   // wave-uniform
#pragma unroll
            for (int j = 0; j < 4; ++j) {
                float ixx, ixy, iyy;
                if (s == 0) {            // product-field reflect: S(0)=p0+2*p1
                    ixx = hx[B2][j] + 2.0f * hx[C2][j];
                    ixy = hq[B2][j] + 2.0f * hq[C2][j];
                    iyy = hy[B2][j] + 2.0f * hy[C2][j];
                } else if (s == HH - 1) { // S(255)=2*p254+p255
                    ixx = 2.0f * hx[A][j] + hx[B2][j];
                    ixy = 2.0f * hq[A][j] + hq[B2][j];
                    iyy = 2.0f * hy[A][j] + hy[B2][j];
                } else {
                    ixx = hx[A][j] + hx[B2][j] + hx[C2][j];
                    ixy = hq[A][j] + hq[B2][j] + hq[C2][j];
                    iyy = hy[A][j] + hy[B2][j] + hy[C2][j];
                }
                float tr = ixx + iyy;
                float Rj = (ixx * iyy - ixy * ixy) - KH * tr * tr;
                Rj = vs ? Rj : NEGINF;
                R[i % 3][j] = Rj;
                rmax = fmaxf(rmax, Rj);
            }
        }

        // Rv row r = m-2 (R rows r-1,r,r+1 at slots (i+1)%3,(i+2)%3,i%3)
        if (i >= 4) {
            const int r = r0 - 4 + i;       // in [r0, r0+RS-1]
            const int A = (i + 1) % 3, B2 = (i + 2) % 3, C2 = i % 3;
            float4 o;
            o.x = fmaxf(fmaxf(R[A][0], R[B2][0]), R[C2][0]);
            o.y = fmaxf(fmaxf(R[A][1], R[B2][1]), R[C2][1]);
            o.z = fmaxf(fmaxf(R[A][2], R[B2][2]), R[C2][2]);
            o.w = fmaxf(fmaxf(R[A][3], R[B2][3]), R[C2][3]);
            *(float4*)(rb + r * WW + c0) = o;
        }
    }

    // per-slab max: block = exactly 4 slabs of one image, plain store
#pragma unroll
    for (int off = 32; off; off >>= 1) rmax = fmaxf(rmax, __shfl_xor(rmax, off));
    __shared__ float sm[4];
    if ((tid & 63) == 0) sm[tid >> 6] = rmax;
    __syncthreads();
    if (tid == 0) {
        float mm = fmaxf(fmaxf(sm[0], sm[1]), fmaxf(sm[2], sm[3]));
        ms[(img << 2) | (blockIdx.x & 3)] = mm;
    }
}

// K2: block = one (b,h) row, 512 threads / 8 waves.
// Stage x[64ch][256px] (64KB) + W[64][64] (16KB) in LDS once; wave w computes
// out-channels 8w..8w+7, lane l pixels 4l..4l+3 (acc 8x4 in VGPRs). x values
// get 8x reuse from LDS; W reads are wave-uniform broadcasts. Epilogue does
// horizontal dilate via shuffles, threshold (per-channel max of 4 slab maxima,
// precomputed in LDS), combine, float4 store.
__global__ __launch_bounds__(512, 4) void k2(const float* __restrict__ x,
                                             const float* __restrict__ wgt,
                                             const float* __restrict__ bias,
                                             const float* __restrict__ ms,
                                             float* __restrict__ io)
{
    __shared__ __align__(16) float Xl[CH][WW];   // 64 KiB
    __shared__ __align__(16) float Wl[CH][CH];   // 16 KiB
    __shared__ float tmax[CH];
    const int tid = threadIdx.x;
    const int wv  = tid >> 6;        // wave 0..7
    const int l   = tid & 63;        // lane 0..63
    const int b   = blockIdx.x >> 8;
    const int h   = blockIdx.x & 255;
    const int oc0 = wv << 3;         // this wave's first out-channel

    // ---- stage x row-block + weights + per-channel thresholds into LDS ----
    {
        const float* xrow = x + (size_t)b * CH * HWSZ + (size_t)h * WW + (l << 2);
        float4 tmp[8];
#pragma unroll
        for (int k = 0; k < 8; ++k)
            tmp[k] = *(const float4*)(xrow + (size_t)(oc0 + k) * HWSZ);
#pragma unroll
        for (int k = 0; k < 8; ++k)
            *(float4*)&Xl[oc0 + k][l << 2] = tmp[k];

        const float4* wg4 = (const float4*)wgt;        // 4096 floats = 1024 float4
        float4* wl4 = (float4*)&Wl[0][0];
        float4 w0 = wg4[tid], w1 = wg4[tid + 512];
        wl4[tid] = w0; wl4[tid + 512] = w1;

        if (tid < CH) {
            float4 m4 = *(const float4*)(ms + ((b * CH + tid) << 2));
            tmax[tid] = TFRAC * fmaxf(fmaxf(m4.x, m4.y), fmaxf(m4.z, m4.w));
        }
    }
    __syncthreads();

    // ---- conv1x1: acc[j][k] = bias + sum_ci W[oc0+j][ci] * x[ci][4l+k] ----
    float acc[8][4];
#pragma unroll
    for (int j = 0; j < 8; ++j) {
        const float bj = bias[oc0 + j];
        acc[j][0] = bj; acc[j][1] = bj; acc[j][2] = bj; acc[j][3] = bj;
    }
#pragma unroll 4
    for (int c2 = 0; c2 < CH; c2 += 2) {
        const float4 xa = *(const float4*)&Xl[c2][l << 2];
        const float4 xb = *(const float4*)&Xl[c2 + 1][l << 2];
#pragma unroll
        for (int j = 0; j < 8; ++j) {
            const float2 wj = *(const float2*)&Wl[oc0 + j][c2];
            acc[j][0] = fmaf(wj.x, xa.x, acc[j][0]);
            acc[j][1] = fmaf(wj.x, xa.y, acc[j][1]);
            acc[j][2] = fmaf(wj.x, xa.z, acc[j][2]);
            acc[j][3] = fmaf(wj.x, xa.w, acc[j][3]);
            acc[j][0] = fmaf(wj.y, xb.x, acc[j][0]);
            acc[j][1] = fmaf(wj.y, xb.y, acc[j][1]);
            acc[j][2] = fmaf(wj.y, xb.z, acc[j][2]);
            acc[j][3] = fmaf(wj.y, xb.w, acc[j][3]);
        }
    }

    // ---- epilogue: horizontal dilate of Rv + threshold + combine ----
    const size_t pb = (size_t)b * CH * HWSZ + (size_t)h * WW + (size_t)(l << 2);
    float4 rvv[8];
#pragma unroll
    for (int j = 0; j < 8; ++j)
        rvv[j] = *(const float4*)(io + pb + (size_t)(oc0 + j) * HWSZ);

#pragma unroll
    for (int j = 0; j < 8; ++j) {
        const int c = oc0 + j;
        float lf = __shfl_up(rvv[j].w, 1);
        float rt = __shfl_down(rvv[j].x, 1);
        if (l == 0)  lf = NEGINF;    // col -1: border does not contribute
        if (l == 63) rt = NEGINF;    // col 256
        const float d0 = fmaxf(fmaxf(lf,       rvv[j].x), rvv[j].y);
        const float d1 = fmaxf(fmaxf(rvv[j].x, rvv[j].y), rvv[j].z);
        const float d2 = fmaxf(fmaxf(rvv[j].y, rvv[j].z), rvv[j].w);
        const float d3 = fmaxf(fmaxf(rvv[j].z, rvv[j].w), rt);
        const float t = tmax[c];
        const float4 xi = *(const float4*)&Xl[c][l << 2];
        const float y0 = fmaxf(acc[j][0], 0.0f);
        const float y1 = fmaxf(acc[j][1], 0.0f);
        const float y2 = fmaxf(acc[j][2], 0.0f);
        const float y3 = fmaxf(acc[j][3], 0.0f);
        float4 o;
        o.x = fmaf(d0 > t ? 1.0f : (d0 < t ? 0.0f : xi.x), y0, xi.x);
        o.y = fmaf(d1 > t ? 1.0f : (d1 < t ? 0.0f : xi.y), y1, xi.y);
        o.z = fmaf(d2 > t ? 1.0f : (d2 < t ? 0.0f : xi.z), y2, xi.z);
        o.w = fmaf(d3 > t ? 1.0f : (d3 < t ? 0.0f : xi.w), y3, xi.w);
        *(float4*)(io + pb + (size_t)c * HWSZ) = o;
    }
}

extern "C" void kernel_launch(void* const* d_in, const int* in_sizes, int n_in,
                              void* d_out, int out_size, void* d_ws, size_t ws_size,
                              hipStream_t stream)
{
    const float* x    = (const float*)d_in[0];
    const float* wgt  = (const float*)d_in[1];
    const float* bias = (const float*)d_in[2];
    float* out = (float*)d_out;
    float* ms = (float*)d_ws;        // NIMG*4 slab maxima (8 KiB)

    hipLaunchKernelGGL(k1, dim3(NIMG * 4), dim3(256), 0, stream, x, out, ms);
    hipLaunchKernelGGL(k2, dim3(BATCH * HH), dim3(512), 0, stream,
                       x, wgt, bias, ms, out);
}

// Round 3
// 307.268 us; speedup vs baseline: 1.4256x; 1.0706x over previous
//
#include <hip/hip_runtime.h>

#define HH 256
#define WW 256
#define BATCH 8
#define CH 64
#define NIMG (BATCH*CH)      // 512
#define HWSZ (HH*WW)         // 65536
#define SCL (1.0f/12.0f)
#define KH 0.04f
#define TFRAC 0.7f
#define RS 16                // rows per thread-tile in K1
#define NEGINF (-__builtin_inff())

// K1: register-rolling Harris. Thread = 4 cols x RS rows; one wave = full
// 256-col row slab, column halos via lane shuffles. Image rows are prefetched
// one iteration ahead (raw float4 in a register, expanded at consume time) so
// the global-load latency is covered by a full iteration of ALU work.
// Each block (4 slabs = 64 rows) plain-stores its max to ms[img*4+slab].
__global__ __launch_bounds__(256) void k1(const float* __restrict__ x,
                                          float* __restrict__ rv,
                                          float* __restrict__ ms)
{
    const int tid = threadIdx.x;
    const int img = blockIdx.x >> 2;                     // 4 blocks per image
    const int tx  = tid & 63;                            // col chunk (4 cols)
    const int sy  = ((blockIdx.x & 3) << 2) | (tid >> 6);// row slab 0..15 (wave-uniform)
    const int r0  = sy * RS;
    const int c0  = tx * 4;
    const float* ib = x + (size_t)img * HWSZ;
    float* rb = rv + (size_t)img * HWSZ;

    float im[3][8];                        // expanded img rows, cols c0-2..c0+5
    float hx[3][4], hq[3][4], hy[3][4];    // horizontal 3-sums of products
    float R[3][4];                         // R rows window, cols c0..c0+3
    float rmax = NEGINF;

    auto loadraw = [&](int gr) -> float4 {
        gr = gr < 0 ? -gr : (gr >= HH ? 2*HH - 2 - gr : gr);   // reflect101
        return *(const float4*)(ib + gr * WW + c0);
    };
    auto expand = [&](float4 own, float* d) {
        float upz = __shfl_up(own.z, 1);     // lane-1 col 4l-2
        float upw = __shfl_up(own.w, 1);     // lane-1 col 4l-1
        float dnx = __shfl_down(own.x, 1);   // lane+1 col 4l+4
        float dny = __shfl_down(own.y, 1);   // lane+1 col 4l+5
        d[0] = (tx > 0)  ? upz : own.z;      // col -2 -> reflect 2
        d[1] = (tx > 0)  ? upw : own.y;      // col -1 -> reflect 1
        d[2] = own.x; d[3] = own.y; d[4] = own.z; d[5] = own.w;
        d[6] = (tx < 63) ? dnx : own.z;      // col 256 -> reflect 254
        d[7] = (tx < 63) ? dny : own.y;      // col 257 -> reflect 253
    };

    expand(loadraw(r0 - 3), im[0]);
    expand(loadraw(r0 - 2), im[1]);
    float4 raw = loadraw(r0 - 1);            // pending for iteration 0

#pragma unroll
    for (int i = 0; i < RS + 4; ++i) {
        const int m = r0 - 2 + i;          // product-row index this step
        expand(raw, im[(2 + i) % 3]);      // row m+1 (loaded last iteration)
        if (i < RS + 3) raw = loadraw(m + 2);   // prefetch next row

        // products row m from img rows m-1,m,m+1; fold to horizontal 3-sums
        {
            const int ia = i % 3, ib2 = (i + 1) % 3, ic = (i + 2) % 3;
            float t1[8], t2[8];
#pragma unroll
            for (int q = 0; q < 8; ++q) {
                t1[q] = im[ia][q] + 2.0f * im[ib2][q] + im[ic][q];
                t2[q] = im[ic][q] - im[ia][q];
            }
            float pxv[6], pqv[6], pyv[6];
#pragma unroll
            for (int q = 0; q < 6; ++q) {
                float dx = SCL * (t1[q + 2] - t1[q]);
                float dy = SCL * (t2[q] + 2.0f * t2[q + 1] + t2[q + 2]);
                pxv[q] = dx * dx;
                pqv[q] = dx * dy;
                pyv[q] = dy * dy;
            }
            // Box stage reflects the product FIELD: pxy(-1) = +pxy(1), but
            // recomputing from the reflected image gives -pxy(1) (dx odd, dy
            // even under column reflection). pxx/pyy are even -> already OK.
            if (tx == 0)  pqv[0] = -pqv[0];   // col -1
            if (tx == 63) pqv[5] = -pqv[5];   // col 256
            const int po = i % 3;
#pragma unroll
            for (int j = 0; j < 4; ++j) {
                hx[po][j] = pxv[j] + pxv[j + 1] + pxv[j + 2];
                hq[po][j] = pqv[j] + pqv[j + 1] + pqv[j + 2];
                hy[po][j] = pyv[j] + pyv[j + 1] + pyv[j + 2];
            }
        }

        // R row s = m-1 (h rows s-1,s,s+1 at slots (i+1)%3,(i+2)%3,i%3)
        if (i >= 2) {
            const int s = m - 1;
            const int A = (i + 1) % 3, B2 = (i + 2) % 3, C2 = i % 3;
            const bool vs = (s >= 0) && (s < HH);   // wave-uniform
#pragma unroll
            for (int j = 0; j < 4; ++j) {
                float ixx, ixy, iyy;
                if (s == 0) {            // product-field reflect: S(0)=p0+2*p1
                    ixx = hx[B2][j] + 2.0f * hx[C2][j];
                    ixy = hq[B2][j] + 2.0f * hq[C2][j];
                    iyy = hy[B2][j] + 2.0f * hy[C2][j];
                } else if (s == HH - 1) { // S(255)=2*p254+p255
                    ixx = 2.0f * hx[A][j] + hx[B2][j];
                    ixy = 2.0f * hq[A][j] + hq[B2][j];
                    iyy = 2.0f * hy[A][j] + hy[B2][j];
                } else {
                    ixx = hx[A][j] + hx[B2][j] + hx[C2][j];
                    ixy = hq[A][j] + hq[B2][j] + hq[C2][j];
                    iyy = hy[A][j] + hy[B2][j] + hy[C2][j];
                }
                float tr = ixx + iyy;
                float Rj = (ixx * iyy - ixy * ixy) - KH * tr * tr;
                Rj = vs ? Rj : NEGINF;
                R[i % 3][j] = Rj;
                rmax = fmaxf(rmax, Rj);
            }
        }

        // Rv row r = m-2 (R rows r-1,r,r+1 at slots (i+1)%3,(i+2)%3,i%3)
        if (i >= 4) {
            const int r = r0 - 4 + i;       // in [r0, r0+RS-1]
            const int A = (i + 1) % 3, B2 = (i + 2) % 3, C2 = i % 3;
            float4 o;
            o.x = fmaxf(fmaxf(R[A][0], R[B2][0]), R[C2][0]);
            o.y = fmaxf(fmaxf(R[A][1], R[B2][1]), R[C2][1]);
            o.z = fmaxf(fmaxf(R[A][2], R[B2][2]), R[C2][2]);
            o.w = fmaxf(fmaxf(R[A][3], R[B2][3]), R[C2][3]);
            *(float4*)(rb + r * WW + c0) = o;
        }
    }

    // per-slab max: block = exactly 4 slabs of one image, plain store
#pragma unroll
    for (int off = 32; off; off >>= 1) rmax = fmaxf(rmax, __shfl_xor(rmax, off));
    __shared__ float sm[4];
    if ((tid & 63) == 0) sm[tid >> 6] = rmax;
    __syncthreads();
    if (tid == 0) {
        float mm = fmaxf(fmaxf(sm[0], sm[1]), fmaxf(sm[2], sm[3]));
        ms[(img << 2) | (blockIdx.x & 3)] = mm;
    }
}

// K2: block = one (b,h) row, 512 threads / 8 waves. Xl staged via
// global_load_lds (wave-uniform LDS base + lane*16 = exactly our layout).
// Weights are wave-uniform -> read straight from global through the scalar
// path (readfirstlane-forced SGPR index), no Wl in LDS: 66 KB LDS -> 2
// blocks/CU (was 82 KB -> 1). Epilogue rv loads issued BEFORE the GEMV so
// their latency hides under the 2048 FMAs. Accumulation order over channels
// identical to the previous passing version -> bitwise-same conv result.
__global__ __launch_bounds__(512, 4) void k2(const float* __restrict__ x,
                                             const float* __restrict__ wgt,
                                             const float* __restrict__ bias,
                                             const float* __restrict__ ms,
                                             float* __restrict__ io)
{
    __shared__ __align__(16) float Xl[CH][WW];   // 64 KiB
    __shared__ float tmax[CH];
    const int tid = threadIdx.x;
    const int wv  = tid >> 6;        // wave 0..7
    const int l   = tid & 63;        // lane 0..63
    const int b   = blockIdx.x >> 8;
    const int h   = blockIdx.x & 255;
    const int oc0 = __builtin_amdgcn_readfirstlane(wv << 3);  // SGPR: wave's first out-ch

    // ---- stage x row-block into LDS via async DMA; thresholds into LDS ----
    {
        const float* xrow = x + (size_t)b * CH * HWSZ + (size_t)h * WW + (l << 2);
#pragma unroll
        for (int k = 0; k < 8; ++k) {
            __builtin_amdgcn_global_load_lds(
                (const __attribute__((address_space(1))) unsigned int*)(xrow + (size_t)(oc0 + k) * HWSZ),
                (__attribute__((address_space(3))) unsigned int*)&Xl[oc0 + k][0],
                16, 0, 0);
        }
        if (tid < CH) {
            float4 m4 = *(const float4*)(ms + ((b * CH + tid) << 2));
            tmax[tid] = TFRAC * fmaxf(fmaxf(m4.x, m4.y), fmaxf(m4.z, m4.w));
        }
    }
    __syncthreads();

    // ---- issue epilogue rv loads early: latency hides under the GEMV ----
    const size_t pb = (size_t)b * CH * HWSZ + (size_t)h * WW + (size_t)(l << 2);
    float4 rvv[8];
#pragma unroll
    for (int j = 0; j < 8; ++j)
        rvv[j] = *(const float4*)(io + pb + (size_t)(oc0 + j) * HWSZ);

    // ---- conv1x1: acc[j][k] = bias + sum_ci W[oc0+j][ci] * x[ci][4l+k] ----
    float acc[8][4];
#pragma unroll
    for (int j = 0; j < 8; ++j) {
        const float bj = bias[oc0 + j];
        acc[j][0] = bj; acc[j][1] = bj; acc[j][2] = bj; acc[j][3] = bj;
    }
#pragma unroll 2
    for (int c4 = 0; c4 < CH; c4 += 4) {
        const float4 xa = *(const float4*)&Xl[c4][l << 2];
        const float4 xb = *(const float4*)&Xl[c4 + 1][l << 2];
        const float4 xc = *(const float4*)&Xl[c4 + 2][l << 2];
        const float4 xd = *(const float4*)&Xl[c4 + 3][l << 2];
#pragma unroll
        for (int j = 0; j < 8; ++j) {
            const float4 wj = *(const float4*)(wgt + (oc0 + j) * CH + c4);  // scalar load
            acc[j][0] = fmaf(wj.x, xa.x, acc[j][0]);
            acc[j][1] = fmaf(wj.x, xa.y, acc[j][1]);
            acc[j][2] = fmaf(wj.x, xa.z, acc[j][2]);
            acc[j][3] = fmaf(wj.x, xa.w, acc[j][3]);
            acc[j][0] = fmaf(wj.y, xb.x, acc[j][0]);
            acc[j][1] = fmaf(wj.y, xb.y, acc[j][1]);
            acc[j][2] = fmaf(wj.y, xb.z, acc[j][2]);
            acc[j][3] = fmaf(wj.y, xb.w, acc[j][3]);
            acc[j][0] = fmaf(wj.z, xc.x, acc[j][0]);
            acc[j][1] = fmaf(wj.z, xc.y, acc[j][1]);
            acc[j][2] = fmaf(wj.z, xc.z, acc[j][2]);
            acc[j][3] = fmaf(wj.z, xc.w, acc[j][3]);
            acc[j][0] = fmaf(wj.w, xd.x, acc[j][0]);
            acc[j][1] = fmaf(wj.w, xd.y, acc[j][1]);
            acc[j][2] = fmaf(wj.w, xd.z, acc[j][2]);
            acc[j][3] = fmaf(wj.w, xd.w, acc[j][3]);
        }
    }

    // ---- epilogue: horizontal dilate of Rv + threshold + combine ----
#pragma unroll
    for (int j = 0; j < 8; ++j) {
        const int c = oc0 + j;
        float lf = __shfl_up(rvv[j].w, 1);
        float rt = __shfl_down(rvv[j].x, 1);
        if (l == 0)  lf = NEGINF;    // col -1: border does not contribute
        if (l == 63) rt = NEGINF;    // col 256
        const float d0 = fmaxf(fmaxf(lf,       rvv[j].x), rvv[j].y);
        const float d1 = fmaxf(fmaxf(rvv[j].x, rvv[j].y), rvv[j].z);
        const float d2 = fmaxf(fmaxf(rvv[j].y, rvv[j].z), rvv[j].w);
        const float d3 = fmaxf(fmaxf(rvv[j].z, rvv[j].w), rt);
        const float t = tmax[c];
        const float4 xi = *(const float4*)&Xl[c][l << 2];
        const float y0 = fmaxf(acc[j][0], 0.0f);
        const float y1 = fmaxf(acc[j][1], 0.0f);
        const float y2 = fmaxf(acc[j][2], 0.0f);
        const float y3 = fmaxf(acc[j][3], 0.0f);
        float4 o;
        o.x = fmaf(d0 > t ? 1.0f : (d0 < t ? 0.0f : xi.x), y0, xi.x);
        o.y = fmaf(d1 > t ? 1.0f : (d1 < t ? 0.0f : xi.y), y1, xi.y);
        o.z = fmaf(d2 > t ? 1.0f : (d2 < t ? 0.0f : xi.z), y2, xi.z);
        o.w = fmaf(d3 > t ? 1.0f : (d3 < t ? 0.0f : xi.w), y3, xi.w);
        *(float4*)(io + pb + (size_t)c * HWSZ) = o;
    }
}

extern "C" void kernel_launch(void* const* d_in, const int* in_sizes, int n_in,
                              void* d_out, int out_size, void* d_ws, size_t ws_size,
                              hipStream_t stream)
{
    const float* x    = (const float*)d_in[0];
    const float* wgt  = (const float*)d_in[1];
    const float* bias = (const float*)d_in[2];
    float* out = (float*)d_out;
    float* ms = (float*)d_ws;        // NIMG*4 slab maxima (8 KiB)

    hipLaunchKernelGGL(k1, dim3(NIMG * 4), dim3(256), 0, stream, x, out, ms);
    hipLaunchKernelGGL(k2, dim3(BATCH * HH), dim3(512), 0, stream,
                       x, wgt, bias, ms, out);
}